// Round 1
// baseline (344.604 us; speedup 1.0000x reference)
//
#include <hip/hip_runtime.h>
#include <hip/hip_bf16.h>
#include <float.h>
#include <math.h>

#define N_TOK 16384
#define DIM   2048
#define NE    64
#define ROWS  128        // 64 gate rows + 64 noise rows
#define TB    32         // tokens per block
#define KT    64         // K tile
#define KTP   68         // padded leading dim (floats): 2-way bank aliasing only
#define EPSF  1e-9f

// ---------- wave-wide helpers (wave64) ----------
__device__ __forceinline__ float wave_sum(float v) {
#pragma unroll
    for (int d = 32; d > 0; d >>= 1) v += __shfl_xor(v, d, 64);
    return v;
}

// max with lowest-index tie-break (matches jax.lax.top_k ordering)
__device__ __forceinline__ void wave_argmax(float v, int i, float& mv, int& mi) {
    float bv = v; int bi = i;
#pragma unroll
    for (int d = 32; d > 0; d >>= 1) {
        float ov = __shfl_xor(bv, d, 64);
        int   oi = __shfl_xor(bi, d, 64);
        if (ov > bv || (ov == bv && oi < bi)) { bv = ov; bi = oi; }
    }
    mv = bv; mi = bi;
}

// ---------- main fused kernel: GEMM (x @ [Wg;Wn]^T) + router epilogue ----------
__global__ __launch_bounds__(256, 2) void router_kernel(
    const float* __restrict__ x,      // [N_TOK][DIM]
    const float* __restrict__ noise,  // [N_TOK][NE]
    const float* __restrict__ Wg,     // [NE][DIM]
    const float* __restrict__ Wn,     // [NE][DIM]
    float* __restrict__ out,          // topi(2N) | weights(2N) | priority(N) | aux(1)
    float* __restrict__ accum)        // ws: importance[64] | load[64]
{
    __shared__ float xs[TB][KTP];
    __shared__ float wsh[ROWS][KTP];
    __shared__ float logi[TB][ROWS + 1];
    __shared__ float s_part[4][2][NE];

    const int t  = threadIdx.x;
    const int og = t & 15;   // output group 0..15 -> experts og + 16j
    const int tg = t >> 4;   // token group  0..15 -> tokens  tg + 16i
    const int tokBase = blockIdx.x * TB;

    float acc[2][8];
#pragma unroll
    for (int i = 0; i < 2; ++i)
#pragma unroll
        for (int j = 0; j < 8; ++j) acc[i][j] = 0.f;

    for (int k0 = 0; k0 < DIM; k0 += KT) {
        // stage x tile: 32 rows x 16 float4 = 512 float4 / 256 thr = 2 each
#pragma unroll
        for (int r = 0; r < 2; ++r) {
            int idx = t + 256 * r;
            int row = idx >> 4, c4 = idx & 15;
            float4 v = *(const float4*)(x + (size_t)(tokBase + row) * DIM + k0 + c4 * 4);
            *(float4*)&xs[row][c4 * 4] = v;
        }
        // stage W tile: 128 rows x 16 float4 = 2048 / 256 = 8 each
#pragma unroll
        for (int r = 0; r < 8; ++r) {
            int idx = t + 256 * r;
            int row = idx >> 4, c4 = idx & 15;
            const float* src = (row < NE) ? (Wg + (size_t)row * DIM)
                                          : (Wn + (size_t)(row - NE) * DIM);
            float4 v = *(const float4*)(src + k0 + c4 * 4);
            *(float4*)&wsh[row][c4 * 4] = v;
        }
        __syncthreads();

#pragma unroll 4
        for (int kk4 = 0; kk4 < KT / 4; ++kk4) {
            float4 xv[2], wv[8];
#pragma unroll
            for (int i = 0; i < 2; ++i)
                xv[i] = *(const float4*)&xs[tg + 16 * i][kk4 * 4];
#pragma unroll
            for (int j = 0; j < 8; ++j)
                wv[j] = *(const float4*)&wsh[og + 16 * j][kk4 * 4];
#pragma unroll
            for (int i = 0; i < 2; ++i)
#pragma unroll
                for (int j = 0; j < 8; ++j) {
                    acc[i][j] += xv[i].x * wv[j].x;
                    acc[i][j] += xv[i].y * wv[j].y;
                    acc[i][j] += xv[i].z * wv[j].z;
                    acc[i][j] += xv[i].w * wv[j].w;
                }
        }
        __syncthreads();
    }

    // scatter accumulators to LDS: logi[tok][expert-row]
#pragma unroll
    for (int i = 0; i < 2; ++i)
#pragma unroll
        for (int j = 0; j < 8; ++j)
            logi[tg + 16 * i][og + 16 * j] = acc[i][j];
    __syncthreads();

    // ---------- per-token router epilogue: wave w handles 8 tokens, lane = expert ----------
    const int wv_id = t >> 6;      // 0..3
    const int lane  = t & 63;      // expert id
    float imp_acc = 0.f, load_acc = 0.f;

    for (int tt = 0; tt < TB / 4; ++tt) {
        const int tok = wv_id * (TB / 4) + tt;
        const int gt  = tokBase + tok;

        float logit = logi[tok][lane];
        float rawn  = logi[tok][NE + lane];
        // softplus (stable, matches jax.nn.softplus) + EPS
        float sp   = fmaxf(rawn, 0.f) + log1pf(expf(-fabsf(rawn)));
        float nstd = sp + EPSF;
        float nz   = noise[(size_t)gt * NE + lane];
        float noisy = logit + nz * nstd;

        // top-3 of 64 lanes
        float v0, v1, v2; int i0, i1, i2d;
        wave_argmax(noisy, lane, v0, i0);
        float m1 = (lane == i0) ? -FLT_MAX : noisy;
        wave_argmax(m1, lane, v1, i1);
        float m2 = (lane == i0 || lane == i1) ? -FLT_MAX : noisy;
        wave_argmax(m2, lane, v2, i2d);
        (void)i2d;

        // softmax over the two surviving entries (max = v0)
        float e1 = expf(v1 - v0);
        float den = 1.f + e1;
        float w0v = 1.f / den;
        float w1v = e1 / den;

        if (lane == 0) {
            out[2 * gt]                 = (float)i0;   // topi
            out[2 * gt + 1]             = (float)i1;
            out[2 * N_TOK + 2 * gt]     = w0v;         // weights
            out[2 * N_TOK + 2 * gt + 1] = w1v;
            out[4 * N_TOK + gt]         = w0v;         // priority = max weight
        }

        // importance contribution (gates_full row is zero except top-2)
        imp_acc += (lane == i0) ? w0v : ((lane == i1) ? w1v : 0.f);

        // load contribution: Phi((logits - kth_excl)/(noise_std+EPS))
        bool in_topk = (lane == i0) || (lane == i1);
        float kth = in_topk ? v2 : v1;
        float z = (logit - kth) / (nstd + EPSF);
        load_acc += 0.5f * (1.f + erff(z * 0.7071067811865476f));
    }

    s_part[wv_id][0][lane] = imp_acc;
    s_part[wv_id][1][lane] = load_acc;
    __syncthreads();

    if (t < 2 * NE) {
        int which = t >> 6, e = t & 63;
        float s = s_part[0][which][e] + s_part[1][which][e]
                + s_part[2][which][e] + s_part[3][which][e];
        atomicAdd(&accum[which * NE + e], s);
    }
}

// ---------- finalize: aux = 0.1*cv2(importance) + 0.1*cv2(load) ----------
__global__ void finalize_kernel(const float* __restrict__ accum,
                                float* __restrict__ out_aux) {
    const int lane = threadIdx.x;  // 64 threads
    float imp  = accum[lane];
    float load = accum[NE + lane];

    float m_imp = wave_sum(imp) * (1.f / NE);
    float di = imp - m_imp;
    float var_imp = wave_sum(di * di) * (1.f / NE);

    float m_load = wave_sum(load) * (1.f / NE);
    float dl = load - m_load;
    float var_load = wave_sum(dl * dl) * (1.f / NE);

    if (lane == 0) {
        out_aux[0] = 0.1f * (var_imp  / (m_imp  * m_imp  + EPSF))
                   + 0.1f * (var_load / (m_load * m_load + EPSF));
    }
}

extern "C" void kernel_launch(void* const* d_in, const int* in_sizes, int n_in,
                              void* d_out, int out_size, void* d_ws, size_t ws_size,
                              hipStream_t stream) {
    const float* x     = (const float*)d_in[0];
    const float* noise = (const float*)d_in[1];
    const float* Wg    = (const float*)d_in[2];
    const float* Wn    = (const float*)d_in[3];
    float* out   = (float*)d_out;
    float* accum = (float*)d_ws;

    hipMemsetAsync(d_ws, 0, 2 * NE * sizeof(float), stream);
    router_kernel<<<N_TOK / TB, 256, 0, stream>>>(x, noise, Wg, Wn, out, accum);
    finalize_kernel<<<1, 64, 0, stream>>>(accum, out + 5 * (size_t)N_TOK);
}